// Round 1
// 409.470 us; speedup vs baseline: 1.0931x; 1.0931x over previous
//
#include <hip/hip_runtime.h>
#include <hip/hip_bf16.h>
#include <stdint.h>

#define SQL 2048
#define EMB 1024
#define NHD 16
#define HDD 64

typedef __bf16 bf16x8 __attribute__((ext_vector_type(8)));
typedef __bf16 bf16x4 __attribute__((ext_vector_type(4)));
typedef float f32x4 __attribute__((ext_vector_type(4)));

__device__ __forceinline__ f32x4 mfma16(bf16x8 a, bf16x8 b, f32x4 c) {
    return __builtin_amdgcn_mfma_f32_16x16x32_bf16(a, b, c, 0, 0, 0);
}

// async global->LDS, 16B per lane. lds must be wave-uniform base; HW adds lane*16.
__device__ __forceinline__ void gload_lds16(const __bf16* g, __bf16* lds) {
    __builtin_amdgcn_global_load_lds(
        (const __attribute__((address_space(1))) uint32_t*)g,
        (__attribute__((address_space(3))) uint32_t*)lds,
        16, 0, 0);
}

// ---------------- fp32 -> bf16 cast ----------------
__global__ void cast_bf16_kernel(const float* __restrict__ in, __bf16* __restrict__ out, int n4) {
    int i = blockIdx.x * blockDim.x + threadIdx.x;
    if (i >= n4) return;
    float4 v = ((const float4*)in)[i];
    bf16x4 o;
    o[0] = (__bf16)v.x; o[1] = (__bf16)v.y; o[2] = (__bf16)v.z; o[3] = (__bf16)v.w;
    ((bf16x4*)out)[i] = o;
}

// ---------------- GEMM: C = (A @ B^T + bias) * scale ----------------
// A: [M,K] bf16 row-major, B: [N,K] bf16 row-major. grid.z selects (B,bias,out,scale).
// 128x128 tile, BK=32, m97 structure: linear LDS + global_load_lds width-16 staging.
template<bool OUT_BF16>
__global__ __launch_bounds__(256, 2)
void gemm_bt(const __bf16* __restrict__ A,
             const __bf16* __restrict__ B0, const __bf16* __restrict__ B1, const __bf16* __restrict__ B2,
             const float* __restrict__ bias0, const float* __restrict__ bias1, const float* __restrict__ bias2,
             void* __restrict__ out0, void* __restrict__ out1, void* __restrict__ out2,
             float s0, float s1, float s2,
             int M, int N, int K)
{
    const __bf16* B = B0; const float* bias = bias0; void* Cout = out0; float cscale = s0;
    if (blockIdx.z == 1) { B = B1; bias = bias1; Cout = out1; cscale = s1; }
    if (blockIdx.z == 2) { B = B2; bias = bias2; Cout = out2; cscale = s2; }

    // linear [128][32] (64B rows) — required by global_load_lds (wave-uniform dest + lane*16)
    __shared__ __attribute__((aligned(16))) __bf16 As[128 * 32];
    __shared__ __attribute__((aligned(16))) __bf16 Bs[128 * 32];

    const int tid  = threadIdx.x;
    const int lane = tid & 63;
    const int wave = tid >> 6;
    const int lrow = lane & 15;
    const int quad = lane >> 4;
    const int bm = blockIdx.y * 128;
    const int bn = blockIdx.x * 128;
    const int wm = (wave >> 1) * 64;
    const int wn = (wave & 1) * 64;

    const f32x4 fzero = {0.f, 0.f, 0.f, 0.f};
    f32x4 acc[4][4];
#pragma unroll
    for (int i = 0; i < 4; i++)
#pragma unroll
        for (int j = 0; j < 4; j++) acc[i][j] = fzero;

    // staging geometry: chunk = 16 rows x 32 cols = 1KB = 64 lanes x 16B.
    // wave w stages chunks {2w, 2w+1} of A and of B.
    const int srow = (lane >> 2);        // 0..15 row within chunk
    const int scol = (lane & 3) * 8;     // 0,8,16,24 elem col

    for (int k0 = 0; k0 < K; k0 += 32) {
        __syncthreads();
#pragma unroll
        for (int i = 0; i < 2; i++) {
            int rbase = wave * 32 + i * 16;
            gload_lds16(&A[(size_t)(bm + rbase + srow) * K + k0 + scol], &As[rbase * 32]);
            gload_lds16(&B[(size_t)(bn + rbase + srow) * K + k0 + scol], &Bs[rbase * 32]);
        }
        __syncthreads();
        bf16x8 af[4], bfr[4];
#pragma unroll
        for (int i = 0; i < 4; i++) af[i]  = *(const bf16x8*)&As[(wm + i * 16 + lrow) * 32 + quad * 8];
#pragma unroll
        for (int i = 0; i < 4; i++) bfr[i] = *(const bf16x8*)&Bs[(wn + i * 16 + lrow) * 32 + quad * 8];
#pragma unroll
        for (int mi = 0; mi < 4; mi++)
#pragma unroll
            for (int ni = 0; ni < 4; ni++)
                acc[mi][ni] = mfma16(af[mi], bfr[ni], acc[mi][ni]);
    }

    // epilogue: C/D layout col=lane&15, row=quad*4+reg
#pragma unroll
    for (int mi = 0; mi < 4; mi++) {
        int row = bm + wm + mi * 16 + quad * 4;
#pragma unroll
        for (int ni = 0; ni < 4; ni++) {
            int col = bn + wn + ni * 16 + lrow;
            float bv = bias[col];
#pragma unroll
            for (int r = 0; r < 4; r++) {
                float v = (acc[mi][ni][r] + bv) * cscale;
                if (OUT_BF16) ((__bf16*)Cout)[(size_t)(row + r) * N + col] = (__bf16)v;
                else          ((float*)Cout)[(size_t)(row + r) * N + col] = v;
            }
        }
    }
}

// ---------------- V transpose: Vt[e][s] = V[s][e] ----------------
__global__ __launch_bounds__(256, 2)
void transpose_v(const __bf16* __restrict__ V, __bf16* __restrict__ Vt) {
    __shared__ __attribute__((aligned(16))) __bf16 tile[64][72];
    const int tid = threadIdx.x;
    const int s0 = blockIdx.x * 64;
    const int c0 = blockIdx.y * 64;
#pragma unroll
    for (int i = 0; i < 2; i++) {
        int lin = tid + i * 256;
        int r  = lin >> 3;
        int cg = (lin & 7) << 3;
        *(bf16x8*)&tile[r][cg] = *(const bf16x8*)&V[(size_t)(s0 + r) * EMB + c0 + cg];
    }
    __syncthreads();
#pragma unroll
    for (int i = 0; i < 2; i++) {
        int lin = tid + i * 256;
        int c  = lin >> 3;
        int sg = (lin & 7) << 3;
        bf16x8 t;
#pragma unroll
        for (int j = 0; j < 8; j++) t[j] = tile[sg + j][c];
        *(bf16x8*)&Vt[(size_t)(c0 + c) * SQL + s0 + sg] = t;
    }
}

// ---------------- fused attention (flash-style w/ recompute) ----------------
// SWAPPED-operand QK^T: st = mfma(K, Q) -> D[k][q], col=lane&15 = q-row.
// Each lane owns ONE q row: softmax state m,l are per-lane SCALARS;
// per-tile reduce = 15 in-reg fmax/adds + 2 shuffles (xor16, xor32).
// Q is pre-scaled by 1/32 in the QKV GEMM epilogue (exact pow2 in bf16).
__global__ __launch_bounds__(256, 2)
void attn_kernel(const __bf16* __restrict__ Qg, const __bf16* __restrict__ Kg,
                 const __bf16* __restrict__ Vt, float* __restrict__ attn,
                 __bf16* __restrict__ ctx)
{
    __shared__ __attribute__((aligned(16))) __bf16 Ks[64][72];
    __shared__ __attribute__((aligned(16))) __bf16 Vs[64][72];   // Vs[d][k] = V[k0+k][h*64+d]
    __shared__ __attribute__((aligned(16))) __bf16 Ps[4][16][72]; // per-wave [q][k] bf16 P

    const int tid  = threadIdx.x;
    const int lane = tid & 63;
    const int w    = tid >> 6;
    const int lrow = lane & 15;
    const int quad = lane >> 4;
    const int h  = blockIdx.y;
    const int q0 = blockIdx.x * 64;
    const f32x4 fzero = {0.f, 0.f, 0.f, 0.f};

    // Q B-fragments (row = lane&15 = this lane's q row), held for whole kernel
    const size_t qoff = (size_t)(q0 + w * 16 + lrow) * EMB + h * HDD;
    const bf16x8 qf0 = *(const bf16x8*)&Qg[qoff + quad * 8];
    const bf16x8 qf1 = *(const bf16x8*)&Qg[qoff + 32 + quad * 8];

    float m = -1e30f, l = 0.f;

    // ---- pass 1: per-row max + sumexp (online, lane-local) ----
    for (int k0 = 0; k0 < SQL; k0 += 64) {
        __syncthreads();
#pragma unroll
        for (int i = 0; i < 2; i++) {
            int lin = tid + i * 256;
            int r  = lin >> 3;
            int cg = (lin & 7) << 3;
            *(bf16x8*)&Ks[r][cg] = *(const bf16x8*)&Kg[(size_t)(k0 + r) * EMB + h * HDD + cg];
        }
        __syncthreads();
        f32x4 st[4];
#pragma unroll
        for (int nt = 0; nt < 4; nt++) {
            bf16x8 b0 = *(const bf16x8*)&Ks[nt * 16 + lrow][quad * 8];
            bf16x8 b1 = *(const bf16x8*)&Ks[nt * 16 + lrow][32 + quad * 8];
            f32x4 a = mfma16(b0, qf0, fzero);   // swapped: D[k=quad*4+r][q=lane&15]
            a = mfma16(b1, qf1, a);
            st[nt] = a;
        }
        float tm = -1e30f;
#pragma unroll
        for (int nt = 0; nt < 4; nt++)
#pragma unroll
            for (int r = 0; r < 4; r++) tm = fmaxf(tm, st[nt][r]);
        tm = fmaxf(tm, __shfl_xor(tm, 16));
        tm = fmaxf(tm, __shfl_xor(tm, 32));
        float mn = fmaxf(m, tm);
        float rs = 0.f;
#pragma unroll
        for (int nt = 0; nt < 4; nt++)
#pragma unroll
            for (int r = 0; r < 4; r++) rs += __expf(st[nt][r] - mn);
        rs += __shfl_xor(rs, 16);
        rs += __shfl_xor(rs, 32);
        l = l * __expf(m - mn) + rs;
        m = mn;
    }

    const float rinv = 1.f / l;

    f32x4 o[4];
#pragma unroll
    for (int nt = 0; nt < 4; nt++) o[nt] = fzero;

    // per-lane attn row pointer (this lane's q row)
    float* __restrict__ arow = attn + (size_t)h * SQL * SQL + (size_t)(q0 + w * 16 + lrow) * SQL;

    // ---- pass 2: recompute S, write attn (f32x4), O += P @ V ----
    for (int k0 = 0; k0 < SQL; k0 += 64) {
        __syncthreads();
#pragma unroll
        for (int i = 0; i < 2; i++) {
            int lin = tid + i * 256;
            int r  = lin >> 3;
            int cg = (lin & 7) << 3;
            *(bf16x8*)&Ks[r][cg] = *(const bf16x8*)&Kg[(size_t)(k0 + r) * EMB + h * HDD + cg];
            *(bf16x8*)&Vs[r][cg] = *(const bf16x8*)&Vt[(size_t)(h * HDD + r) * SQL + k0 + cg];
        }
        __syncthreads();
#pragma unroll
        for (int nt = 0; nt < 4; nt++) {
            bf16x8 b0 = *(const bf16x8*)&Ks[nt * 16 + lrow][quad * 8];
            bf16x8 b1 = *(const bf16x8*)&Ks[nt * 16 + lrow][32 + quad * 8];
            f32x4 a = mfma16(b0, qf0, fzero);
            a = mfma16(b1, qf1, a);
            f32x4 pv;
            bf16x4 pb;
#pragma unroll
            for (int r = 0; r < 4; r++) {
                float p = __expf(a[r] - m) * rinv;
                pv[r] = p;
                pb[r] = (__bf16)p;
            }
            // lane's 4 regs are consecutive k: one 16B store per nt, 64B/row segments
            *(f32x4*)&arow[k0 + nt * 16 + quad * 4] = pv;
            *(bf16x4*)&Ps[w][lrow][nt * 16 + quad * 4] = pb;  // [q][k] transpose via LDS
        }
        // read back P as A-fragments (wave-local buffer, in-order ds ops)
        bf16x8 pf0 = *(const bf16x8*)&Ps[w][lrow][quad * 8];
        bf16x8 pf1 = *(const bf16x8*)&Ps[w][lrow][32 + quad * 8];
#pragma unroll
        for (int nt = 0; nt < 4; nt++) {
            bf16x8 v0 = *(const bf16x8*)&Vs[nt * 16 + lrow][quad * 8];
            bf16x8 v1 = *(const bf16x8*)&Vs[nt * 16 + lrow][32 + quad * 8];
            o[nt] = mfma16(pf0, v0, o[nt]);
            o[nt] = mfma16(pf1, v1, o[nt]);
        }
    }

    // O layout: D[q=quad*4+r][d=nt*16+lane&15] (unchanged from before)
#pragma unroll
    for (int nt = 0; nt < 4; nt++)
#pragma unroll
        for (int r = 0; r < 4; r++)
            ctx[(size_t)(q0 + w * 16 + quad * 4 + r) * EMB + h * HDD + nt * 16 + lrow] = (__bf16)o[nt][r];
}

// ---------------- launch ----------------
extern "C" void kernel_launch(void* const* d_in, const int* in_sizes, int n_in,
                              void* d_out, int out_size, void* d_ws, size_t ws_size,
                              hipStream_t stream)
{
    const float* x  = (const float*)d_in[0];
    const float* Wq = (const float*)d_in[1];
    const float* bq = (const float*)d_in[2];
    const float* Wk = (const float*)d_in[3];
    const float* bk = (const float*)d_in[4];
    const float* Wv = (const float*)d_in[5];
    const float* bv = (const float*)d_in[6];
    const float* Wo = (const float*)d_in[7];
    const float* bo = (const float*)d_in[8];

    float* out  = (float*)d_out;
    float* attn = out + (size_t)SQL * EMB;

    // workspace layout (bf16 elements), total 16M elems = 32 MB
    const size_t M1 = 1u << 20;
    __bf16* wsb = (__bf16*)d_ws;
    __bf16* xb  = wsb;            // 2M
    __bf16* wqb = wsb + 2 * M1;   // 1M
    __bf16* wkb = wsb + 3 * M1;   // 1M
    __bf16* wvb = wsb + 4 * M1;   // 1M
    __bf16* wob = wsb + 5 * M1;   // 1M
    __bf16* Qb  = wsb + 6 * M1;   // 2M
    __bf16* Kb  = wsb + 8 * M1;   // 2M
    __bf16* Vb  = wsb + 10 * M1;  // 2M
    __bf16* Vtb = wsb + 12 * M1;  // 2M
    __bf16* ctb = wsb + 14 * M1;  // 2M

    cast_bf16_kernel<<<(SQL * EMB / 4 + 255) / 256, 256, 0, stream>>>(x,  xb,  SQL * EMB / 4);
    cast_bf16_kernel<<<(EMB * EMB / 4 + 255) / 256, 256, 0, stream>>>(Wq, wqb, EMB * EMB / 4);
    cast_bf16_kernel<<<(EMB * EMB / 4 + 255) / 256, 256, 0, stream>>>(Wk, wkb, EMB * EMB / 4);
    cast_bf16_kernel<<<(EMB * EMB / 4 + 255) / 256, 256, 0, stream>>>(Wv, wvb, EMB * EMB / 4);
    cast_bf16_kernel<<<(EMB * EMB / 4 + 255) / 256, 256, 0, stream>>>(Wo, wob, EMB * EMB / 4);

    // Q,K,V = x @ W^T + b   (one launch, grid.z picks weight; Q scaled by 1/32 = exact pow2)
    gemm_bt<true><<<dim3(EMB / 128, SQL / 128, 3), 256, 0, stream>>>(
        xb, wqb, wkb, wvb, bq, bk, bv,
        (void*)Qb, (void*)Kb, (void*)Vb,
        0.03125f, 1.0f, 1.0f, SQL, EMB, EMB);

    transpose_v<<<dim3(SQL / 64, EMB / 64), 256, 0, stream>>>(Vb, Vtb);

    attn_kernel<<<dim3(SQL / 64, NHD), 256, 0, stream>>>(Qb, Kb, Vtb, attn, ctb);

    // out = ctx @ Wo^T + bo  (fp32 output)
    gemm_bt<false><<<dim3(EMB / 128, SQL / 128, 1), 256, 0, stream>>>(
        ctb, wob, wob, wob, bo, bo, bo,
        (void*)out, (void*)out, (void*)out,
        1.0f, 1.0f, 1.0f, SQL, EMB, EMB);
}